// Round 9
// baseline (1284.506 us; speedup 1.0000x reference)
//
#include <hip/hip_runtime.h>

// DCRNN (DCE'd): 65536 independent sequences, 12 steps, 2-layer GRU-lite, H=64.
// fp32 vector-ALU implementation (no fp32 MFMA on CDNA4).
//
// Round-9: weights via VMEM (vmcnt) + h via LDS (lgkmcnt) — SEPARATE counters.
// Round-8's s_load weights shared lgkmcnt with ds_read and SMEM is
// out-of-order -> compiler emitted a full lgkmcnt(0) drain (~250cyc L2) per
// k-step; waves were ~89% stalled. Now: weight pointers are NOT
// readfirstlane'd (stay "divergent") -> global_load_dwordx4 broadcast loads,
// manually double-buffered 2 ksteps ahead (named float4 regs, no arrays);
// h float2 prefetched 1 pair ahead. Both load streams use counted, in-order
// waits the compiler can pipeline. 8 waves x 128 seqs/block, 2 seqs/lane,
// wave owns 8 cols x {u,c}. __launch_bounds__(512,4): 128-VGPR budget,
// LDS (69.6KB) caps at 2 blocks/CU = 4 waves/SIMD.

#define TSTEPS 12

__device__ __forceinline__ float fsig(float z) {
    z = fminf(fmaxf(z, -30.f), 30.f);
    return 1.f / (1.f + __expf(-z));
}
__device__ __forceinline__ float ftanh(float z) {
    z = fminf(fmaxf(z, -15.f), 15.f);
    float e = __expf(2.f * z);
    return 1.f - 2.f / (e + 1.f);
}

// ---- workspace layout (floats) ----
// [0, 8192)       L0h : [k(64)][w(8)][16]  (j<8: Wu0[2+k][w*8+j], else Wc0)
// [8192, 8448)    L0x : [k(2)][w(8)][16]   rows 0..1 of Wu0/Wc0
// [8448, 24832)   L1h : [k(128)][w(8)][16] rows of Wu1/Wc1
// [24832, 24960)  B0  : [w(8)][16]  bu0|bc0
// [24960, 25088)  B1  : [w(8)][16]  bu1|bc1
// [25088, 25152)  Wo  : 64
// [25152]         bo

__global__ void pack_weights(const float* __restrict__ Wu0, const float* __restrict__ bu0,
                             const float* __restrict__ Wc0, const float* __restrict__ bc0,
                             const float* __restrict__ Wu1, const float* __restrict__ bu1,
                             const float* __restrict__ Wc1, const float* __restrict__ bc1,
                             const float* __restrict__ Wo, const float* __restrict__ bo,
                             float* __restrict__ Wp) {
    const int tid = blockIdx.x * blockDim.x + threadIdx.x;
    const int nthr = gridDim.x * blockDim.x;
    for (int i = tid; i < 8192; i += nthr) {
        const int k = i >> 7, r = i & 127, wv = r >> 4, j = r & 15;
        const int col = wv * 8 + (j & 7);
        Wp[i] = (j < 8) ? Wu0[(2 + k) * 64 + col] : Wc0[(2 + k) * 64 + col];
    }
    for (int i = tid; i < 256; i += nthr) {
        const int k = i >> 7, r = i & 127, wv = r >> 4, j = r & 15;
        const int col = wv * 8 + (j & 7);
        Wp[8192 + i] = (j < 8) ? Wu0[k * 64 + col] : Wc0[k * 64 + col];
    }
    for (int i = tid; i < 16384; i += nthr) {
        const int k = i >> 7, r = i & 127, wv = r >> 4, j = r & 15;
        const int col = wv * 8 + (j & 7);
        Wp[8448 + i] = (j < 8) ? Wu1[k * 64 + col] : Wc1[k * 64 + col];
    }
    for (int i = tid; i < 128; i += nthr) {
        const int wv = i >> 4, j = i & 15;
        const int col = wv * 8 + (j & 7);
        Wp[24832 + i] = (j < 8) ? bu0[col] : bc0[col];
        Wp[24960 + i] = (j < 8) ? bu1[col] : bc1[col];
    }
    for (int i = tid; i < 64; i += nthr) Wp[25088 + i] = Wo[i];
    if (tid == 0) Wp[25152] = bo[0];
}

// ---- macro machinery: 8 cols x 2 gates x 2 seqs, all named regs ----
#define F(a, b, c) __builtin_fmaf((a), (b), (c))
#define REP8(X) X(0) X(1) X(2) X(3) X(4) X(5) X(6) X(7)

#define INITJ(J) zu##J##0 = bp_[J]; zu##J##1 = bp_[J]; \
                 zc##J##0 = bp_[8 + J]; zc##J##1 = bp_[8 + J];

// one k-step: HV=(h[seq0],h[seq1]); P0/P1 = u-cols 0-3/4-7; P2/P3 = c-cols
#define KCOMP(HV, P0, P1, P2, P3) \
  zu00=F(HV.x,P0.x,zu00); zu01=F(HV.y,P0.x,zu01); zc00=F(HV.x,P2.x,zc00); zc01=F(HV.y,P2.x,zc01); \
  zu10=F(HV.x,P0.y,zu10); zu11=F(HV.y,P0.y,zu11); zc10=F(HV.x,P2.y,zc10); zc11=F(HV.y,P2.y,zc11); \
  zu20=F(HV.x,P0.z,zu20); zu21=F(HV.y,P0.z,zu21); zc20=F(HV.x,P2.z,zc20); zc21=F(HV.y,P2.z,zc21); \
  zu30=F(HV.x,P0.w,zu30); zu31=F(HV.y,P0.w,zu31); zc30=F(HV.x,P2.w,zc30); zc31=F(HV.y,P2.w,zc31); \
  zu40=F(HV.x,P1.x,zu40); zu41=F(HV.y,P1.x,zu41); zc40=F(HV.x,P3.x,zc40); zc41=F(HV.y,P3.x,zc41); \
  zu50=F(HV.x,P1.y,zu50); zu51=F(HV.y,P1.y,zu51); zc50=F(HV.x,P3.y,zc50); zc51=F(HV.y,P3.y,zc51); \
  zu60=F(HV.x,P1.z,zu60); zu61=F(HV.y,P1.z,zu61); zc60=F(HV.x,P3.z,zc60); zc61=F(HV.y,P3.z,zc61); \
  zu70=F(HV.x,P1.w,zu70); zu71=F(HV.y,P1.w,zu71); zc70=F(HV.x,P3.w,zc70); zc71=F(HV.y,P3.w,zc71);

// load 2 ksteps of this wave's weights (8 float4) from BASE (float4*, VMEM)
#define LOADW(N, BASE, KK) { \
    const float4* q_ = (BASE) + (size_t)(KK) * 32; \
    w##N##0 = q_[0];  w##N##1 = q_[1];  w##N##2 = q_[2];  w##N##3 = q_[3]; \
    w##N##4 = q_[32]; w##N##5 = q_[33]; w##N##6 = q_[34]; w##N##7 = q_[35]; }

#define LDH(HV, KK) HV = *(const float2*)(Aptr + (size_t)(KK) * 128);

#define ACTJ(J) { \
    const float2 ho = *(const float2*)(hb_ + (J) * 128); \
    float u_, c_; \
    u_ = fsig(zu##J##0); c_ = ftanh(zc##J##0); \
    zu##J##0 = F(u_, ho.x, (1.f - u_) * c_); \
    u_ = fsig(zu##J##1); c_ = ftanh(zc##J##1); \
    zu##J##1 = F(u_, ho.y, (1.f - u_) * c_); }

#define STJ(J) *(float2*)(hb_ + (J) * 128) = make_float2(zu##J##0, zu##J##1);

#define POJ(J) part0 = F(zu##J##0, wo_[J], part0); \
               part1 = F(zu##J##1, wo_[J], part1);

__global__ __launch_bounds__(512, 4) void dcrnn_main(const float* __restrict__ x,
                                                     const float* __restrict__ Wp,
                                                     float* __restrict__ out) {
    __shared__ float A[128 * 128];  // A[k][2*lane+p]: k 0..63 = h0, 64..127 = h1
    __shared__ float P[8 * 128];    // per-wave output partials

    const int tid = threadIdx.x;
    const int lane = tid & 63;
    const int w = tid >> 6;  // NOT readfirstlane'd: keep weight ptrs "divergent" -> VMEM

    const int s0 = blockIdx.x * 128;
    const int b = s0 >> 11;
    const int n0 = s0 & 2047;

    const float4* Wq0 = (const float4*)Wp + w * 4;             // L0h
    const float4* Wqx = (const float4*)(Wp + 8192) + w * 4;    // L0x
    const float4* Wq1 = (const float4*)(Wp + 8448) + w * 4;    // L1h
    const float* B0w = Wp + 24832 + w * 16;
    const float* B1w = Wp + 24960 + w * 16;

    for (int i = tid; i < 128 * 128; i += 512) A[i] = 0.f;
    __syncthreads();

    const float* Aptr = A + 2 * lane;
    float* hb0 = A + (size_t)(w * 8) * 128 + 2 * lane;         // wave's h0 cols
    float* hb1 = A + (size_t)(64 + w * 8) * 128 + 2 * lane;    // wave's h1 cols

    const float* xlane = x + (size_t)(b * TSTEPS) * 4096 + (size_t)(n0 + 2 * lane) * 2;

    float zu00, zu01, zu10, zu11, zu20, zu21, zu30, zu31;
    float zu40, zu41, zu50, zu51, zu60, zu61, zu70, zu71;
    float zc00, zc01, zc10, zc11, zc20, zc21, zc30, zc31;
    float zc40, zc41, zc50, zc51, zc60, zc61, zc70, zc71;
    float4 wA0, wA1, wA2, wA3, wA4, wA5, wA6, wA7;
    float4 wB0, wB1, wB2, wB3, wB4, wB5, wB6, wB7;
    float2 hA0, hA1, hB0, hB1;

#pragma unroll 1
    for (int t = 0; t < TSTEPS; ++t) {
        const float4 xv = *(const float4*)(xlane + (size_t)t * 4096);

        // ===== layer 0: z = b0 + h0_old @ W0h + x @ W0x =====
        { const float* bp_ = B0w; REP8(INITJ) }
        LOADW(A, Wq0, 0) LDH(hA0, 0) LDH(hA1, 1)
#pragma unroll 1
        for (int k = 0; k < 64; k += 4) {
            LOADW(B, Wq0, k + 2) LDH(hB0, k + 2) LDH(hB1, k + 3)
            KCOMP(hA0, wA0, wA1, wA2, wA3)
            KCOMP(hA1, wA4, wA5, wA6, wA7)
            LOADW(A, Wq0, k + 4) LDH(hA0, k + 4) LDH(hA1, k + 5)   // over-read @k=60: guarded by L0x region / unused
            KCOMP(hB0, wB0, wB1, wB2, wB3)
            KCOMP(hB1, wB4, wB5, wB6, wB7)
        }
        {
            LOADW(A, Wqx, 0)
            const float2 xa_ = make_float2(xv.x, xv.z);
            const float2 xb_ = make_float2(xv.y, xv.w);
            KCOMP(xa_, wA0, wA1, wA2, wA3)
            KCOMP(xb_, wA4, wA5, wA6, wA7)
        }
        { const float* hb_ = hb0; REP8(ACTJ) }   // zuJp <- h0_new
        __syncthreads();  // (1) all reads of h0_old done
        { float* hb_ = hb0; REP8(STJ) }
        __syncthreads();  // (2) h0_new visible

        // ===== layer 1: z = b1 + [h0_new|h1_old] @ W1h =====
        { const float* bp_ = B1w; REP8(INITJ) }
        LOADW(A, Wq1, 0) LDH(hA0, 0) LDH(hA1, 1)
#pragma unroll 1
        for (int k = 0; k < 128; k += 4) {
            LOADW(B, Wq1, k + 2) LDH(hB0, k + 2) LDH(hB1, k + 3)
            KCOMP(hA0, wA0, wA1, wA2, wA3)
            KCOMP(hA1, wA4, wA5, wA6, wA7)
            LOADW(A, Wq1, k + 4) LDH(hA0, k + 4) LDH(hA1, k + 5)   // over-read @k=124: B0/B1 region + P LDS, unused
            KCOMP(hB0, wB0, wB1, wB2, wB3)
            KCOMP(hB1, wB4, wB5, wB6, wB7)
        }
        { const float* hb_ = hb1; REP8(ACTJ) }   // zuJp <- h1_new
        __syncthreads();  // (3) all layer-1 reads (h0_new, h1_old) done
        { float* hb_ = hb1; REP8(STJ) }
        // no 4th barrier: next-step layer-0 consumes only h0 rows; its h1-row
        // over-read values are never used, and real h1 reads at t+1 sit
        // behind t+1's barriers (1)+(2).
    }

    // ===== epilogue: out = h1 @ Wo + bo  (h1 still in zu regs) =====
    float part0 = 0.f, part1 = 0.f;
    { const float* wo_ = Wp + 25088 + w * 8; REP8(POJ) }
    *(float2*)&P[w * 128 + 2 * lane] = make_float2(part0, part1);
    __syncthreads();
    if (tid < 128) {
        float acc = Wp[25152];
#pragma unroll
        for (int wv = 0; wv < 8; ++wv) acc += P[wv * 128 + tid];
        out[s0 + tid] = acc;
    }
}

extern "C" void kernel_launch(void* const* d_in, const int* in_sizes, int n_in,
                              void* d_out, int out_size, void* d_ws, size_t ws_size,
                              hipStream_t stream) {
    const float* x   = (const float*)d_in[0];
    // d_in[1] supports, d_in[2] Wr0, d_in[3] br0 : dead code in reference
    const float* Wu0 = (const float*)d_in[4];
    const float* bu0 = (const float*)d_in[5];
    const float* Wc0 = (const float*)d_in[6];
    const float* bc0 = (const float*)d_in[7];
    // d_in[8] Wd0, d_in[9] bd0, d_in[10] Wr1, d_in[11] br1 : dead
    const float* Wu1 = (const float*)d_in[12];
    const float* bu1 = (const float*)d_in[13];
    const float* Wc1 = (const float*)d_in[14];
    const float* bc1 = (const float*)d_in[15];
    // d_in[16] Wd1, d_in[17] bd1 : dead
    const float* Wo  = (const float*)d_in[18];
    const float* bo  = (const float*)d_in[19];

    float* Wp = (float*)d_ws;  // ~101 KB

    hipLaunchKernelGGL(pack_weights, dim3(64), dim3(256), 0, stream,
                       Wu0, bu0, Wc0, bc0, Wu1, bu1, Wc1, bc1, Wo, bo, Wp);
    hipLaunchKernelGGL(dcrnn_main, dim3(65536 / 128), dim3(512), 0, stream,
                       x, Wp, (float*)d_out);
}